// Round 6
// baseline (1098.828 us; speedup 1.0000x reference)
//
#include <hip/hip_runtime.h>

#define DEVFN __device__ __forceinline__

namespace {

constexpr int NN = 50000;   // nodes
constexpr int NE = 600000;  // edges
constexpr int H  = 128;
constexpr float LN_EPS = 1e-6f;

typedef _Float16 f16x8 __attribute__((ext_vector_type(8)));
typedef _Float16 f16x4 __attribute__((ext_vector_type(4)));
typedef float f32x4 __attribute__((ext_vector_type(4)));

// acc[8][4] += xs_tile(8 rows x K) @ W(K x 128) restricted to cols c0..c0+3.
DEVFN void mm_block(const float* xsrow, int pitch, int K,
                    const float* __restrict__ W, int c0, float (&acc)[8][4]) {
  for (int k = 0; k < K; k += 4) {
    float4 w0 = *(const float4*)(W + (size_t)(k + 0) * H + c0);
    float4 w1 = *(const float4*)(W + (size_t)(k + 1) * H + c0);
    float4 w2 = *(const float4*)(W + (size_t)(k + 2) * H + c0);
    float4 w3 = *(const float4*)(W + (size_t)(k + 3) * H + c0);
#pragma unroll
    for (int r = 0; r < 8; ++r) {
      float4 a = *(const float4*)(xsrow + r * pitch + k);
      acc[r][0] += a.x * w0.x; acc[r][0] += a.y * w1.x; acc[r][0] += a.z * w2.x; acc[r][0] += a.w * w3.x;
      acc[r][1] += a.x * w0.y; acc[r][1] += a.y * w1.y; acc[r][1] += a.z * w2.y; acc[r][1] += a.w * w3.y;
      acc[r][2] += a.x * w0.z; acc[r][2] += a.y * w1.z; acc[r][2] += a.z * w2.z; acc[r][2] += a.w * w3.z;
      acc[r][3] += a.x * w0.w; acc[r][3] += a.y * w1.w; acc[r][3] += a.z * w2.w; acc[r][3] += a.w * w3.w;
    }
  }
}

// ---------------- node encoder (2-layer MLP, ReLU between), fp16 out ----------------
template <int K_IN>
__global__ __launch_bounds__(128) void encoder_kernel(
    const float* __restrict__ x, const float* __restrict__ W0,
    const float* __restrict__ b0, const float* __restrict__ W1,
    const float* __restrict__ b1, _Float16* __restrict__ outp, int R) {
  constexpr int PIN = K_IN + 4;
  __shared__ float xs[32 * PIN];
  __shared__ float hs[32 * 132];
  const int t = threadIdx.x;
  const int r0 = blockIdx.x * 32;

  const int nvec = 32 * K_IN / 4;
  for (int i = t; i < nvec; i += 128) {
    int rr = i / (K_IN / 4);
    int kk = (i % (K_IN / 4)) * 4;
    int row = r0 + rr;
    float4 v = make_float4(0.f, 0.f, 0.f, 0.f);
    if (row < R) v = *(const float4*)&x[(size_t)row * K_IN + kk];
    *(float4*)&xs[rr * PIN + kk] = v;
  }
  __syncthreads();

  const int c0 = (t & 31) * 4;
  const int rbase = (t >> 5) * 8;
  float acc[8][4];
  {
    float4 bb = *(const float4*)&b0[c0];
#pragma unroll
    for (int r = 0; r < 8; ++r) { acc[r][0] = bb.x; acc[r][1] = bb.y; acc[r][2] = bb.z; acc[r][3] = bb.w; }
  }
  mm_block(&xs[rbase * PIN], PIN, K_IN, W0, c0, acc);
#pragma unroll
  for (int r = 0; r < 8; ++r) {
    float4 h;
    h.x = fmaxf(acc[r][0], 0.f); h.y = fmaxf(acc[r][1], 0.f);
    h.z = fmaxf(acc[r][2], 0.f); h.w = fmaxf(acc[r][3], 0.f);
    *(float4*)&hs[(rbase + r) * 132 + c0] = h;
  }
  __syncthreads();
  {
    float4 bb = *(const float4*)&b1[c0];
#pragma unroll
    for (int r = 0; r < 8; ++r) { acc[r][0] = bb.x; acc[r][1] = bb.y; acc[r][2] = bb.z; acc[r][3] = bb.w; }
  }
  mm_block(&hs[rbase * 132], 132, H, W1, c0, acc);
#pragma unroll
  for (int r = 0; r < 8; ++r) {
    int row = r0 + rbase + r;
    if (row < R) {
      f16x4 pk = {(_Float16)acc[r][0], (_Float16)acc[r][1],
                  (_Float16)acc[r][2], (_Float16)acc[r][3]};
      *(f16x4*)&outp[(size_t)row * H + c0] = pk;
    }
  }
}

// ---------------- fp32 linear (setup-time small GEMMs) ----------------
__global__ __launch_bounds__(128) void linear_kernel(
    const float* __restrict__ x, const float* __restrict__ W,
    float* __restrict__ y, int R) {
  __shared__ float xs[32 * 132];
  const int t = threadIdx.x;
  const int r0 = blockIdx.x * 32;
  {
    const int r = t & 31, q = t >> 5;
    int row = r0 + r;
    if (row >= R) row = R - 1;
    const float* src = &x[(size_t)row * H + q * 32];
#pragma unroll
    for (int j = 0; j < 8; ++j)
      *(float4*)&xs[r * 132 + q * 32 + j * 4] = *(const float4*)&src[j * 4];
  }
  __syncthreads();
  const int c0 = (t & 31) * 4;
  const int rbase = (t >> 5) * 8;
  float acc[8][4];
#pragma unroll
  for (int r = 0; r < 8; ++r) { acc[r][0] = 0.f; acc[r][1] = 0.f; acc[r][2] = 0.f; acc[r][3] = 0.f; }
  mm_block(&xs[rbase * 132], 132, H, W, c0, acc);
#pragma unroll
  for (int r = 0; r < 8; ++r) {
    int row = r0 + rbase + r;
    if (row < R)
      *(float4*)&y[(size_t)row * H + c0] =
          make_float4(acc[r][0], acc[r][1], acc[r][2], acc[r][3]);
  }
}

// o[j] = sum_k v[k] * W[k*128 + j]
__global__ __launch_bounds__(128) void vecmat_kernel(
    const float* __restrict__ v, const float* __restrict__ W,
    float* __restrict__ o) {
  int j = threadIdx.x;
  float s = 0.f;
  for (int k = 0; k < H; ++k) s += v[k] * W[(size_t)k * H + j];
  o[j] = s;
}

// ---------------- prepack W[K x 128] fp32 -> MFMA B-fragment order, fp16 ----------------
__global__ __launch_bounds__(64) void prepack_kernel(
    const float* __restrict__ W, _Float16* __restrict__ pk) {
  const int ks = blockIdx.x, ct = blockIdx.y, l = threadIdx.x;
  const int kbase = ks * 32 + (l >> 4) * 8;
  const int col = ct * 16 + (l & 15);
  _Float16 tmp[8];
#pragma unroll
  for (int j = 0; j < 8; ++j)
    tmp[j] = (_Float16)W[(size_t)(kbase + j) * H + col];
  *(f16x8*)&pk[((size_t)((ks * 8 + ct) * 64) + l) * 8] = *(f16x8*)tmp;
}

// ---------------- pack B2f fp32 -> MFMA C-layout fp16 ----------------
__global__ __launch_bounds__(64) void packc_kernel(
    const float* __restrict__ B2f, _Float16* __restrict__ B2pk) {
  const int tile = blockIdx.x, l = threadIdx.x;
  const int rbase = tile * 16 + (l >> 4) * 4;
  const int col = (l & 15);
  _Float16 tmp[32];
#pragma unroll
  for (int ct = 0; ct < 8; ++ct)
#pragma unroll
    for (int q = 0; q < 4; ++q)
      tmp[ct * 4 + q] = (_Float16)B2f[(size_t)(rbase + q) * H + ct * 16 + col];
  _Float16* dst = &B2pk[((size_t)tile * 64 + l) * 32];
#pragma unroll
  for (int i = 0; i < 4; ++i)
    *(f16x8*)(dst + i * 8) = *(f16x8*)(tmp + i * 8);
}

// ---------------- counting sort by receiver ----------------
__global__ __launch_bounds__(256) void hist_kernel(const int* __restrict__ recv,
                                                   int* __restrict__ cnt) {
  int i = blockIdx.x * 256 + threadIdx.x;
  if (i < NE) atomicAdd(&cnt[recv[i]], 1);
}

__global__ __launch_bounds__(256) void scan1_kernel(const int* __restrict__ cnt,
                                                    int* __restrict__ excl,
                                                    int* __restrict__ part) {
  __shared__ int s[256];
  int t = threadIdx.x;
  int i = blockIdx.x * 256 + t;
  int v = (i < NN) ? cnt[i] : 0;
  s[t] = v;
  __syncthreads();
  for (int off = 1; off < 256; off <<= 1) {
    int x = (t >= off) ? s[t - off] : 0;
    __syncthreads();
    s[t] += x;
    __syncthreads();
  }
  if (i < NN) excl[i] = s[t] - v;
  if (t == 255) part[blockIdx.x] = s[255];
}

__global__ __launch_bounds__(256) void scan2_kernel(int* __restrict__ part, int nb) {
  __shared__ int s[256];
  int t = threadIdx.x;
  int v = (t < nb) ? part[t] : 0;
  s[t] = v;
  __syncthreads();
  for (int off = 1; off < 256; off <<= 1) {
    int x = (t >= off) ? s[t - off] : 0;
    __syncthreads();
    s[t] += x;
    __syncthreads();
  }
  if (t < nb) part[t] = s[t] - v;
}

__global__ __launch_bounds__(256) void scan3_kernel(int* __restrict__ excl,
                                                    const int* __restrict__ part,
                                                    int* __restrict__ cursor) {
  int i = blockIdx.x * 256 + threadIdx.x;
  if (i < NN) {
    int e = excl[i] + part[i >> 8];
    excl[i] = e;
    cursor[i] = e;
  }
}

__global__ __launch_bounds__(256) void scatter_kernel(
    const int* __restrict__ senders, const int* __restrict__ recv,
    int* __restrict__ cursor, int* __restrict__ sendp,
    int* __restrict__ eperm) {
  int i = blockIdx.x * 256 + threadIdx.x;
  if (i < NE) {
    int r = recv[i];
    int pos = atomicAdd(&cursor[r], 1);
    sendp[pos] = senders[i];
    eperm[pos] = i;
  }
}

// ---------------- degree-sorted node order (scheduling heuristic) ----------------
__global__ __launch_bounds__(256) void dhist_kernel(const int* __restrict__ start,
                                                    const int* __restrict__ endc,
                                                    int* __restrict__ dh) {
  int v = blockIdx.x * 256 + threadIdx.x;
  if (v < NN) {
    int d = endc[v] - start[v];
    if (d > 63) d = 63;
    atomicAdd(&dh[d], 1);
  }
}

__global__ __launch_bounds__(64) void dscan_kernel(const int* __restrict__ dh,
                                                   int* __restrict__ dcur) {
  __shared__ int s[64];
  int t = threadIdx.x;
  int v = dh[t];
  s[t] = v;
  __syncthreads();
  for (int off = 1; off < 64; off <<= 1) {
    int x = (t >= off) ? s[t - off] : 0;
    __syncthreads();
    s[t] += x;
    __syncthreads();
  }
  dcur[t] = s[t] - v;  // exclusive
}

__global__ __launch_bounds__(256) void dscatter_kernel(const int* __restrict__ start,
                                                       const int* __restrict__ endc,
                                                       int* __restrict__ dcur,
                                                       int* __restrict__ vsort) {
  int v = blockIdx.x * 256 + threadIdx.x;
  if (v < NN) {
    int d = endc[v] - start[v];
    if (d > 63) d = 63;
    int pos = atomicAdd(&dcur[d], 1);
    vsort[pos] = v;
  }
}

// ---------------- Hs[v] = sum_{e->v} relu(edges_e @ W0 + b0), atomic-free ----------------
DEVFN void hs_accum(const float* __restrict__ x, const float (&w)[16][4],
                    const float4 bb, float4& a) {
  float4 x0 = *(const float4*)(x + 0);
  float4 x1 = *(const float4*)(x + 4);
  float4 x2 = *(const float4*)(x + 8);
  float4 x3 = *(const float4*)(x + 12);
  float h0 = bb.x, h1 = bb.y, h2 = bb.z, h3 = bb.w;
#define HS_STEP(xx, kk) \
  h0 += (xx) * w[kk][0]; h1 += (xx) * w[kk][1]; h2 += (xx) * w[kk][2]; h3 += (xx) * w[kk][3];
  HS_STEP(x0.x, 0)  HS_STEP(x0.y, 1)  HS_STEP(x0.z, 2)  HS_STEP(x0.w, 3)
  HS_STEP(x1.x, 4)  HS_STEP(x1.y, 5)  HS_STEP(x1.z, 6)  HS_STEP(x1.w, 7)
  HS_STEP(x2.x, 8)  HS_STEP(x2.y, 9)  HS_STEP(x2.z, 10) HS_STEP(x2.w, 11)
  HS_STEP(x3.x, 12) HS_STEP(x3.y, 13) HS_STEP(x3.z, 14) HS_STEP(x3.w, 15)
#undef HS_STEP
  a.x += fmaxf(h0, 0.f);
  a.y += fmaxf(h1, 0.f);
  a.z += fmaxf(h2, 0.f);
  a.w += fmaxf(h3, 0.f);
}

__global__ __launch_bounds__(256, 4) void hs_fused_kernel(
    const float* __restrict__ edges, const int* __restrict__ eperm,
    const int* __restrict__ start, const int* __restrict__ endc,
    const int* __restrict__ vsort,
    const float* __restrict__ W0, const float* __restrict__ b0,
    float* __restrict__ Hs) {
  const int t = threadIdx.x;
  const int v = vsort[blockIdx.x * 4 + (t >> 6)];  // NN % 4 == 0
  const int lane = t & 63;
  const int half = lane >> 5;
  const int c = (lane & 31) * 4;
  float w[16][4];
#pragma unroll
  for (int k = 0; k < 16; ++k) {
    float4 ww = *(const float4*)&W0[(size_t)k * H + c];
    w[k][0] = ww.x; w[k][1] = ww.y; w[k][2] = ww.z; w[k][3] = ww.w;
  }
  const float4 bb = *(const float4*)&b0[c];
  float4 a = make_float4(0.f, 0.f, 0.f, 0.f);
  int j = start[v];
  const int e = endc[v];
  // index-prefetch pipeline: next iteration's eperm pair loads before this
  // iteration's FMAs, breaking the serial eperm->row chain.
  int i0 = 0, i1 = 0;
  if (j + 3 < e) { i0 = eperm[j + half]; i1 = eperm[j + 2 + half]; }
  for (; j + 3 < e;) {
    int jn = j + 4;
    int n0 = 0, n1 = 0;
    if (jn + 3 < e) { n0 = eperm[jn + half]; n1 = eperm[jn + 2 + half]; }
    hs_accum(&edges[(size_t)i0 * 16], w, bb, a);
    hs_accum(&edges[(size_t)i1 * 16], w, bb, a);
    i0 = n0; i1 = n1; j = jn;
  }
  for (; j + 1 < e; j += 2) {
    int e0 = eperm[j + half];
    hs_accum(&edges[(size_t)e0 * 16], w, bb, a);
  }
  if (j < e && half == 0) {
    int e0 = eperm[j];
    hs_accum(&edges[(size_t)e0 * 16], w, bb, a);
  }
  a.x += __shfl_xor(a.x, 32);
  a.y += __shfl_xor(a.y, 32);
  a.z += __shfl_xor(a.z, 32);
  a.w += __shfl_xor(a.w, 32);
  if (half == 0) *(float4*)&Hs[(size_t)v * H + c] = a;
}

// ---------------- B2f[v] = Hs[v] @ Wc2 + deg[v] * bc2 ----------------
__global__ __launch_bounds__(128) void blin_kernel(
    const float* __restrict__ Hs, const float* __restrict__ Wc2,
    const float* __restrict__ bc2, const int* __restrict__ start,
    const int* __restrict__ endc, float* __restrict__ B2f) {
  __shared__ float xs[32 * 132];
  const int t = threadIdx.x;
  const int r0 = blockIdx.x * 32;
  {
    const int r = t & 31, q = t >> 5;
    int row = r0 + r;
    if (row >= NN) row = NN - 1;
    const float* src = &Hs[(size_t)row * H + q * 32];
#pragma unroll
    for (int j = 0; j < 8; ++j)
      *(float4*)&xs[r * 132 + q * 32 + j * 4] = *(const float4*)&src[j * 4];
  }
  __syncthreads();
  const int c0 = (t & 31) * 4;
  const int rbase = (t >> 5) * 8;
  const float4 bc4 = *(const float4*)&bc2[c0];
  float acc[8][4];
#pragma unroll
  for (int r = 0; r < 8; ++r) {
    int row = r0 + rbase + r;
    if (row >= NN) row = NN - 1;
    float deg = (float)(endc[row] - start[row]);
    acc[r][0] = deg * bc4.x; acc[r][1] = deg * bc4.y;
    acc[r][2] = deg * bc4.z; acc[r][3] = deg * bc4.w;
  }
  mm_block(&xs[rbase * 132], 132, H, Wc2, c0, acc);
#pragma unroll
  for (int r = 0; r < 8; ++r) {
    int row = r0 + rbase + r;
    if (row < NN)
      *(float4*)&B2f[(size_t)row * H + c0] =
          make_float4(acc[r][0], acc[r][1], acc[r][2], acc[r][3]);
  }
}

// ---------------- per-pass: S[v] = sum_{s in N(v)} n16[s]  (fp16 gather) ----------------
// 16 lanes per node (full 256B row via f16x8/lane), 4 nodes/wave, 16 nodes/block,
// 4-edge unroll -> up to 16 outstanding row loads per wave. Degree-sorted node
// order (vsort) keeps the 4 nodes in a wave at equal degree (no divergence waste).
__global__ __launch_bounds__(256) void gather_kernel(
    const _Float16* __restrict__ n16, const int* __restrict__ start,
    const int* __restrict__ endc, const int* __restrict__ sendp,
    const int* __restrict__ vsort, _Float16* __restrict__ S) {
  const int t = threadIdx.x;
  const int v = vsort[blockIdx.x * 16 + (t >> 4)];  // NN % 16 == 0
  const int c = (t & 15) * 8;
  float a[8] = {0.f, 0.f, 0.f, 0.f, 0.f, 0.f, 0.f, 0.f};
  int j = start[v];
  const int e = endc[v];
  for (; j + 3 < e; j += 4) {
    int s0 = sendp[j], s1 = sendp[j + 1], s2 = sendp[j + 2], s3 = sendp[j + 3];
    f16x8 p0 = *(const f16x8*)&n16[(size_t)s0 * H + c];
    f16x8 p1 = *(const f16x8*)&n16[(size_t)s1 * H + c];
    f16x8 p2 = *(const f16x8*)&n16[(size_t)s2 * H + c];
    f16x8 p3 = *(const f16x8*)&n16[(size_t)s3 * H + c];
#pragma unroll
    for (int i = 0; i < 8; ++i)
      a[i] += ((float)p0[i] + (float)p1[i]) + ((float)p2[i] + (float)p3[i]);
  }
  for (; j < e; ++j) {
    int s0 = sendp[j];
    f16x8 p0 = *(const f16x8*)&n16[(size_t)s0 * H + c];
#pragma unroll
    for (int i = 0; i < 8; ++i) a[i] += (float)p0[i];
  }
  f16x8 o;
#pragma unroll
  for (int i = 0; i < 8; ++i) o[i] = (_Float16)a[i];
  *(f16x8*)&S[(size_t)v * H + c] = o;
}

// ---------------- MFMA node update ----------------
// pre-act = n@W0t + S@Wf + B2 + b0 ; h = relu(pre-act)
// out = LN(h@W1 + n@Wn + b1)
__global__ __launch_bounds__(256) void node_mfma_kernel(
    const _Float16* __restrict__ n16, const _Float16* __restrict__ S16,
    const _Float16* __restrict__ B2pk,
    const _Float16* __restrict__ pkW0t, const _Float16* __restrict__ pkWf,
    const float* __restrict__ b0,
    const _Float16* __restrict__ pkW1, const _Float16* __restrict__ pkWn,
    const float* __restrict__ b1,
    const float* __restrict__ ln_g, const float* __restrict__ ln_b,
    _Float16* __restrict__ nout) {
  __shared__ _Float16 lds[4][16 * 136];
  const int t = threadIdx.x;
  const int wave = t >> 6, lane = t & 63;
  const int row0 = blockIdx.x * 64 + wave * 16;
  const int quad = lane >> 4, m16 = lane & 15;
  _Float16* hlds = &lds[wave][0];

  int arow = row0 + m16;
  if (arow >= NN) arow = NN - 1;
  const _Float16* nrow = &n16[(size_t)arow * H + quad * 8];
  const _Float16* srow = &S16[(size_t)arow * H + quad * 8];

  const int tile = blockIdx.x * 4 + wave;
  const _Float16* b2l = &B2pk[((size_t)tile * 64 + lane) * 32];
  f32x4 acc[8];
#pragma unroll
  for (int ct = 0; ct < 8; ++ct) {
    float bb = b0[ct * 16 + m16];
    f16x4 bv = *(const f16x4*)(b2l + ct * 4);
    acc[ct] = (f32x4){bb + (float)bv[0], bb + (float)bv[1],
                      bb + (float)bv[2], bb + (float)bv[3]};
  }
#pragma unroll
  for (int ks = 0; ks < 4; ++ks) {
    f16x8 an = *(const f16x8*)(nrow + ks * 32);
    f16x8 as = *(const f16x8*)(srow + ks * 32);
    const _Float16* bp0 = pkW0t + ((size_t)ks * 8 * 64 + lane) * 8;
    const _Float16* bpf = pkWf + ((size_t)ks * 8 * 64 + lane) * 8;
#pragma unroll
    for (int ct = 0; ct < 8; ++ct) {
      f16x8 bw0 = *(const f16x8*)(bp0 + ct * 512);
      acc[ct] = __builtin_amdgcn_mfma_f32_16x16x32_f16(an, bw0, acc[ct], 0, 0, 0);
      f16x8 bwf = *(const f16x8*)(bpf + ct * 512);
      acc[ct] = __builtin_amdgcn_mfma_f32_16x16x32_f16(as, bwf, acc[ct], 0, 0, 0);
    }
  }
#pragma unroll
  for (int ct = 0; ct < 8; ++ct) {
#pragma unroll
    for (int q = 0; q < 4; ++q)
      hlds[(quad * 4 + q) * 136 + ct * 16 + m16] =
          (_Float16)fmaxf(acc[ct][q], 0.f);
  }
  __syncthreads();

  const _Float16* hrow = &hlds[m16 * 136 + quad * 8];
  f32x4 acc2[8];
#pragma unroll
  for (int ct = 0; ct < 8; ++ct) {
    float bb = b1[ct * 16 + m16];
    acc2[ct] = (f32x4){bb, bb, bb, bb};
  }
#pragma unroll
  for (int ks = 0; ks < 4; ++ks) {
    f16x8 ah = *(const f16x8*)(hrow + ks * 32);
    f16x8 an = *(const f16x8*)(nrow + ks * 32);
    const _Float16* bp1 = pkW1 + ((size_t)ks * 8 * 64 + lane) * 8;
    const _Float16* bpn = pkWn + ((size_t)ks * 8 * 64 + lane) * 8;
#pragma unroll
    for (int ct = 0; ct < 8; ++ct) {
      f16x8 b1f = *(const f16x8*)(bp1 + ct * 512);
      acc2[ct] = __builtin_amdgcn_mfma_f32_16x16x32_f16(ah, b1f, acc2[ct], 0, 0, 0);
      f16x8 bnf = *(const f16x8*)(bpn + ct * 512);
      acc2[ct] = __builtin_amdgcn_mfma_f32_16x16x32_f16(an, bnf, acc2[ct], 0, 0, 0);
    }
  }

  float gv[8], bv[8];
#pragma unroll
  for (int ct = 0; ct < 8; ++ct) {
    gv[ct] = ln_g[ct * 16 + m16];
    bv[ct] = ln_b[ct * 16 + m16];
  }
  __syncthreads();
#pragma unroll
  for (int q = 0; q < 4; ++q) {
    float s1 = 0.f, s2 = 0.f;
#pragma unroll
    for (int ct = 0; ct < 8; ++ct) {
      float v = acc2[ct][q];
      s1 += v; s2 += v * v;
    }
#pragma unroll
    for (int m = 1; m <= 8; m <<= 1) {
      s1 += __shfl_xor(s1, m);
      s2 += __shfl_xor(s2, m);
    }
    float mu = s1 * (1.f / 128.f);
    float var = s2 * (1.f / 128.f) - mu * mu;
    float rs = rsqrtf(var + LN_EPS);
#pragma unroll
    for (int ct = 0; ct < 8; ++ct) {
      float o = (acc2[ct][q] - mu) * rs * gv[ct] + bv[ct];
      hlds[(quad * 4 + q) * 136 + ct * 16 + m16] = (_Float16)o;
    }
  }
  __syncthreads();

  {
    int lr = lane >> 2;
    int cc = (lane & 3) * 32;
    const _Float16* src = &hlds[lr * 136 + cc];
    int orow = row0 + lr;
    if (orow < NN) {
      _Float16* dst = &nout[(size_t)orow * H + cc];
      *(f16x8*)(dst + 0)  = *(const f16x8*)(src + 0);
      *(f16x8*)(dst + 8)  = *(const f16x8*)(src + 8);
      *(f16x8*)(dst + 16) = *(const f16x8*)(src + 16);
      *(f16x8*)(dst + 24) = *(const f16x8*)(src + 24);
    }
  }
}

// ---------------- decoder (fp16 node input) ----------------
__global__ __launch_bounds__(128) void decode_kernel(
    const _Float16* __restrict__ n, const float* __restrict__ W0,
    const float* __restrict__ b0, const float* __restrict__ W1,
    const float* __restrict__ b1, float* __restrict__ out) {
  __shared__ float xs[32 * 132];
  __shared__ float hs[32 * 132];
  const int t = threadIdx.x;
  const int r0 = blockIdx.x * 32;
  {
    const int r = t & 31, q = t >> 5;
    int row = r0 + r;
    if (row >= NN) row = NN - 1;
    const _Float16* src = &n[(size_t)row * H + q * 32];
#pragma unroll
    for (int j = 0; j < 4; ++j) {
      f16x8 v8 = *(const f16x8*)&src[j * 8];
#pragma unroll
      for (int i = 0; i < 8; ++i)
        xs[r * 132 + q * 32 + j * 8 + i] = (float)v8[i];
    }
  }
  __syncthreads();
  const int c0 = (t & 31) * 4;
  const int rbase = (t >> 5) * 8;
  float acc[8][4];
  {
    float4 bb = *(const float4*)&b0[c0];
#pragma unroll
    for (int r = 0; r < 8; ++r) { acc[r][0] = bb.x; acc[r][1] = bb.y; acc[r][2] = bb.z; acc[r][3] = bb.w; }
  }
  mm_block(&xs[rbase * 132], 132, H, W0, c0, acc);
#pragma unroll
  for (int r = 0; r < 8; ++r) {
    float4 h;
    h.x = fmaxf(acc[r][0], 0.f); h.y = fmaxf(acc[r][1], 0.f);
    h.z = fmaxf(acc[r][2], 0.f); h.w = fmaxf(acc[r][3], 0.f);
    *(float4*)&hs[(rbase + r) * 132 + c0] = h;
  }
  __syncthreads();
  if (t < 64) {
    int r = t >> 1, c = t & 1;
    float s = b1[c];
    for (int k = 0; k < H; ++k) s += hs[r * 132 + k] * W1[k * 2 + c];
    int row = r0 + r;
    if (row < NN) out[(size_t)row * 2 + c] = s;
  }
}

__global__ __launch_bounds__(256) void zero_kernel(float4* __restrict__ p, int n4) {
  int i = blockIdx.x * 256 + threadIdx.x;
  if (i < n4) p[i] = make_float4(0.f, 0.f, 0.f, 0.f);
}

}  // namespace

extern "C" void kernel_launch(void* const* d_in, const int* in_sizes, int n_in,
                              void* d_out, int out_size, void* d_ws, size_t ws_size,
                              hipStream_t stream) {
  const float* nodes     = (const float*)d_in[0];
  const float* edges     = (const float*)d_in[1];
  const int*   senders   = (const int*)d_in[2];
  const int*   receivers = (const int*)d_in[3];
  const float* enc_n_W0 = (const float*)d_in[4];
  const float* enc_n_b0 = (const float*)d_in[5];
  const float* enc_n_W1 = (const float*)d_in[6];
  const float* enc_n_b1 = (const float*)d_in[7];
  const float* enc_e_W0 = (const float*)d_in[8];
  const float* enc_e_b0 = (const float*)d_in[9];
  const float* enc_e_W1 = (const float*)d_in[10];
  const float* enc_e_b1 = (const float*)d_in[11];
  const float* W_msg    = (const float*)d_in[12];
  const float* node_W0  = (const float*)d_in[13];
  const float* node_b0  = (const float*)d_in[14];
  const float* node_W1  = (const float*)d_in[15];
  const float* node_b1  = (const float*)d_in[16];
  const float* W_node   = (const float*)d_in[17];
  const float* ln_g     = (const float*)d_in[18];
  const float* ln_b     = (const float*)d_in[19];
  const float* dec_W0   = (const float*)d_in[20];
  const float* dec_b0   = (const float*)d_in[21];
  const float* dec_W1   = (const float*)d_in[22];
  const float* dec_b1   = (const float*)d_in[23];
  float* out = (float*)d_out;

  const float* Wt  = W_msg;                // rows 0..127 of W_msg
  const float* Wb  = W_msg + 128 * H;      // rows 128..255
  const float* W0t = node_W0;              // rows 0..127 of node_W0
  const float* W0b = node_W0 + 128 * H;    // rows 128..255

  const int mfmaBlocks = (NN + 63) / 64;   // 782
  const int nTiles     = mfmaBlocks * 4;

  // workspace layout
  float* Hs   = (float*)d_ws;                          // NN*H f32
  float* B2f  = Hs + (size_t)NN * H;                   // NN*H f32
  float* Wc   = B2f + (size_t)NN * H;                  // 128*128 f32
  float* Wc2  = Wc + 128 * H;
  float* Wf32 = Wc2 + 128 * H;
  float* bc   = Wf32 + 128 * H;                        // 128
  float* bc2  = bc + 128;                              // 128
  _Float16* n16a  = (_Float16*)(bc2 + 128);            // NN*H f16
  _Float16* n16b  = n16a + (size_t)NN * H;
  _Float16* S16   = n16b + (size_t)NN * H;
  _Float16* B2pk  = S16 + (size_t)NN * H;              // nTiles*64*32 f16
  _Float16* pkW0t = B2pk + (size_t)nTiles * 64 * 32;
  _Float16* pkWf  = pkW0t + 128 * H;
  _Float16* pkW1  = pkWf + 128 * H;
  _Float16* pkWn  = pkW1 + 128 * H;
  int* cnt    = (int*)(pkWn + 128 * H);
  int* excl   = cnt + NN;
  int* cursor = excl + NN;
  int* vsort  = cursor + NN;               // NN
  int* part   = vsort + NN;                // 256
  int* dh     = part + 256;                // 64
  int* dcur   = dh + 64;                   // 64
  int* sendp  = dcur + 64;                 // NE
  int* eperm  = sendp + NE;                // NE

  const int nodeBlocks = (NN + 31) / 32;     // 1563
  const int scanBlocks = (NN + 255) / 256;   // 196
  const int neBlocks   = (NE + 255) / 256;   // 2344

  // --- one-time: sort edges by receiver ---
  zero_kernel<<<(NN / 4 + 255) / 256, 256, 0, stream>>>((float4*)cnt, NN / 4);
  zero_kernel<<<1, 256, 0, stream>>>((float4*)dh, 16);
  hist_kernel<<<neBlocks, 256, 0, stream>>>(receivers, cnt);
  scan1_kernel<<<scanBlocks, 256, 0, stream>>>(cnt, excl, part);
  scan2_kernel<<<1, 256, 0, stream>>>(part, scanBlocks);
  scan3_kernel<<<scanBlocks, 256, 0, stream>>>(excl, part, cursor);
  scatter_kernel<<<neBlocks, 256, 0, stream>>>(senders, receivers, cursor, sendp, eperm);

  // --- degree-sorted node order ---
  dhist_kernel<<<scanBlocks, 256, 0, stream>>>(excl, cursor, dh);
  dscan_kernel<<<1, 64, 0, stream>>>(dh, dcur);
  dscatter_kernel<<<scanBlocks, 256, 0, stream>>>(excl, cursor, dcur, vsort);

  // --- fold chains:  Wc = W1e@Wb;  Wc2 = Wc@W0b;  Wf = Wt@W0b;  bc2 = (b1e@Wb)@W0b ---
  linear_kernel<<<4, 128, 0, stream>>>(enc_e_W1, Wb, Wc, 128);
  vecmat_kernel<<<1, 128, 0, stream>>>(enc_e_b1, Wb, bc);
  linear_kernel<<<4, 128, 0, stream>>>(Wc, W0b, Wc2, 128);
  vecmat_kernel<<<1, 128, 0, stream>>>(bc, W0b, bc2);
  linear_kernel<<<4, 128, 0, stream>>>(Wt, W0b, Wf32, 128);
  prepack_kernel<<<dim3(4, 8), 64, 0, stream>>>(W0t, pkW0t);
  prepack_kernel<<<dim3(4, 8), 64, 0, stream>>>(Wf32, pkWf);
  prepack_kernel<<<dim3(4, 8), 64, 0, stream>>>(node_W1, pkW1);
  prepack_kernel<<<dim3(4, 8), 64, 0, stream>>>(W_node, pkWn);

  encoder_kernel<32><<<nodeBlocks, 128, 0, stream>>>(
      nodes, enc_n_W0, enc_n_b0, enc_n_W1, enc_n_b1, n16a, NN);
  hs_fused_kernel<<<NN / 4, 256, 0, stream>>>(
      edges, eperm, excl, cursor, vsort, enc_e_W0, enc_e_b0, Hs);
  blin_kernel<<<nodeBlocks, 128, 0, stream>>>(Hs, Wc2, bc2, excl, cursor, B2f);
  packc_kernel<<<NN / 16, 64, 0, stream>>>(B2f, B2pk);

  // --- 5 weight-tied passes ---
  _Float16* ncur = n16a;
  _Float16* nnxt = n16b;
  for (int p = 0; p < 5; ++p) {
    gather_kernel<<<NN / 16, 256, 0, stream>>>(ncur, excl, cursor, sendp, vsort, S16);
    node_mfma_kernel<<<mfmaBlocks, 256, 0, stream>>>(
        ncur, S16, B2pk, pkW0t, pkWf, node_b0, pkW1, pkWn, node_b1,
        ln_g, ln_b, nnxt);
    _Float16* tmp = ncur; ncur = nnxt; nnxt = tmp;
  }

  decode_kernel<<<nodeBlocks, 128, 0, stream>>>(ncur, dec_W0, dec_b0, dec_W1, dec_b1, out);
}

// Round 7
// 749.926 us; speedup vs baseline: 1.4652x; 1.4652x over previous
//
#include <hip/hip_runtime.h>

#define DEVFN __device__ __forceinline__

namespace {

constexpr int NN = 50000;   // nodes
constexpr int NE = 600000;  // edges
constexpr int H  = 128;
constexpr float LN_EPS = 1e-6f;

typedef _Float16 f16x8 __attribute__((ext_vector_type(8)));
typedef _Float16 f16x4 __attribute__((ext_vector_type(4)));
typedef float f32x4 __attribute__((ext_vector_type(4)));

// acc[8][4] += xs_tile(8 rows x K) @ W(K x 128) restricted to cols c0..c0+3.
DEVFN void mm_block(const float* xsrow, int pitch, int K,
                    const float* __restrict__ W, int c0, float (&acc)[8][4]) {
  for (int k = 0; k < K; k += 4) {
    float4 w0 = *(const float4*)(W + (size_t)(k + 0) * H + c0);
    float4 w1 = *(const float4*)(W + (size_t)(k + 1) * H + c0);
    float4 w2 = *(const float4*)(W + (size_t)(k + 2) * H + c0);
    float4 w3 = *(const float4*)(W + (size_t)(k + 3) * H + c0);
#pragma unroll
    for (int r = 0; r < 8; ++r) {
      float4 a = *(const float4*)(xsrow + r * pitch + k);
      acc[r][0] += a.x * w0.x; acc[r][0] += a.y * w1.x; acc[r][0] += a.z * w2.x; acc[r][0] += a.w * w3.x;
      acc[r][1] += a.x * w0.y; acc[r][1] += a.y * w1.y; acc[r][1] += a.z * w2.y; acc[r][1] += a.w * w3.y;
      acc[r][2] += a.x * w0.z; acc[r][2] += a.y * w1.z; acc[r][2] += a.z * w2.z; acc[r][2] += a.w * w3.z;
      acc[r][3] += a.x * w0.w; acc[r][3] += a.y * w1.w; acc[r][3] += a.z * w2.w; acc[r][3] += a.w * w3.w;
    }
  }
}

// ---------------- node encoder (2-layer MLP, ReLU between), fp16 out ----------------
template <int K_IN>
__global__ __launch_bounds__(128) void encoder_kernel(
    const float* __restrict__ x, const float* __restrict__ W0,
    const float* __restrict__ b0, const float* __restrict__ W1,
    const float* __restrict__ b1, _Float16* __restrict__ outp, int R) {
  constexpr int PIN = K_IN + 4;
  __shared__ float xs[32 * PIN];
  __shared__ float hs[32 * 132];
  const int t = threadIdx.x;
  const int r0 = blockIdx.x * 32;

  const int nvec = 32 * K_IN / 4;
  for (int i = t; i < nvec; i += 128) {
    int rr = i / (K_IN / 4);
    int kk = (i % (K_IN / 4)) * 4;
    int row = r0 + rr;
    float4 v = make_float4(0.f, 0.f, 0.f, 0.f);
    if (row < R) v = *(const float4*)&x[(size_t)row * K_IN + kk];
    *(float4*)&xs[rr * PIN + kk] = v;
  }
  __syncthreads();

  const int c0 = (t & 31) * 4;
  const int rbase = (t >> 5) * 8;
  float acc[8][4];
  {
    float4 bb = *(const float4*)&b0[c0];
#pragma unroll
    for (int r = 0; r < 8; ++r) { acc[r][0] = bb.x; acc[r][1] = bb.y; acc[r][2] = bb.z; acc[r][3] = bb.w; }
  }
  mm_block(&xs[rbase * PIN], PIN, K_IN, W0, c0, acc);
#pragma unroll
  for (int r = 0; r < 8; ++r) {
    float4 h;
    h.x = fmaxf(acc[r][0], 0.f); h.y = fmaxf(acc[r][1], 0.f);
    h.z = fmaxf(acc[r][2], 0.f); h.w = fmaxf(acc[r][3], 0.f);
    *(float4*)&hs[(rbase + r) * 132 + c0] = h;
  }
  __syncthreads();
  {
    float4 bb = *(const float4*)&b1[c0];
#pragma unroll
    for (int r = 0; r < 8; ++r) { acc[r][0] = bb.x; acc[r][1] = bb.y; acc[r][2] = bb.z; acc[r][3] = bb.w; }
  }
  mm_block(&hs[rbase * 132], 132, H, W1, c0, acc);
#pragma unroll
  for (int r = 0; r < 8; ++r) {
    int row = r0 + rbase + r;
    if (row < R) {
      f16x4 pk = {(_Float16)acc[r][0], (_Float16)acc[r][1],
                  (_Float16)acc[r][2], (_Float16)acc[r][3]};
      *(f16x4*)&outp[(size_t)row * H + c0] = pk;
    }
  }
}

// ---------------- fp32 linear (setup-time small GEMMs) ----------------
__global__ __launch_bounds__(128) void linear_kernel(
    const float* __restrict__ x, const float* __restrict__ W,
    float* __restrict__ y, int R) {
  __shared__ float xs[32 * 132];
  const int t = threadIdx.x;
  const int r0 = blockIdx.x * 32;
  {
    const int r = t & 31, q = t >> 5;
    int row = r0 + r;
    if (row >= R) row = R - 1;
    const float* src = &x[(size_t)row * H + q * 32];
#pragma unroll
    for (int j = 0; j < 8; ++j)
      *(float4*)&xs[r * 132 + q * 32 + j * 4] = *(const float4*)&src[j * 4];
  }
  __syncthreads();
  const int c0 = (t & 31) * 4;
  const int rbase = (t >> 5) * 8;
  float acc[8][4];
#pragma unroll
  for (int r = 0; r < 8; ++r) { acc[r][0] = 0.f; acc[r][1] = 0.f; acc[r][2] = 0.f; acc[r][3] = 0.f; }
  mm_block(&xs[rbase * 132], 132, H, W, c0, acc);
#pragma unroll
  for (int r = 0; r < 8; ++r) {
    int row = r0 + rbase + r;
    if (row < R)
      *(float4*)&y[(size_t)row * H + c0] =
          make_float4(acc[r][0], acc[r][1], acc[r][2], acc[r][3]);
  }
}

// o[j] = sum_k v[k] * W[k*128 + j]
__global__ __launch_bounds__(128) void vecmat_kernel(
    const float* __restrict__ v, const float* __restrict__ W,
    float* __restrict__ o) {
  int j = threadIdx.x;
  float s = 0.f;
  for (int k = 0; k < H; ++k) s += v[k] * W[(size_t)k * H + j];
  o[j] = s;
}

// ---------------- prepack W[K x 128] fp32 -> MFMA B-fragment order, fp16 ----------------
__global__ __launch_bounds__(64) void prepack_kernel(
    const float* __restrict__ W, _Float16* __restrict__ pk) {
  const int ks = blockIdx.x, ct = blockIdx.y, l = threadIdx.x;
  const int kbase = ks * 32 + (l >> 4) * 8;
  const int col = ct * 16 + (l & 15);
  _Float16 tmp[8];
#pragma unroll
  for (int j = 0; j < 8; ++j)
    tmp[j] = (_Float16)W[(size_t)(kbase + j) * H + col];
  *(f16x8*)&pk[((size_t)((ks * 8 + ct) * 64) + l) * 8] = *(f16x8*)tmp;
}

// ---------------- pack B2f fp32 -> MFMA C-layout fp16 ----------------
__global__ __launch_bounds__(64) void packc_kernel(
    const float* __restrict__ B2f, _Float16* __restrict__ B2pk) {
  const int tile = blockIdx.x, l = threadIdx.x;
  const int rbase = tile * 16 + (l >> 4) * 4;
  const int col = (l & 15);
  _Float16 tmp[32];
#pragma unroll
  for (int ct = 0; ct < 8; ++ct)
#pragma unroll
    for (int q = 0; q < 4; ++q)
      tmp[ct * 4 + q] = (_Float16)B2f[(size_t)(rbase + q) * H + ct * 16 + col];
  _Float16* dst = &B2pk[((size_t)tile * 64 + l) * 32];
#pragma unroll
  for (int i = 0; i < 4; ++i)
    *(f16x8*)(dst + i * 8) = *(f16x8*)(tmp + i * 8);
}

// ---------------- counting sort by receiver ----------------
__global__ __launch_bounds__(256) void hist_kernel(const int* __restrict__ recv,
                                                   int* __restrict__ cnt) {
  int i = blockIdx.x * 256 + threadIdx.x;
  if (i < NE) atomicAdd(&cnt[recv[i]], 1);
}

__global__ __launch_bounds__(256) void scan1_kernel(const int* __restrict__ cnt,
                                                    int* __restrict__ excl,
                                                    int* __restrict__ part) {
  __shared__ int s[256];
  int t = threadIdx.x;
  int i = blockIdx.x * 256 + t;
  int v = (i < NN) ? cnt[i] : 0;
  s[t] = v;
  __syncthreads();
  for (int off = 1; off < 256; off <<= 1) {
    int x = (t >= off) ? s[t - off] : 0;
    __syncthreads();
    s[t] += x;
    __syncthreads();
  }
  if (i < NN) excl[i] = s[t] - v;
  if (t == 255) part[blockIdx.x] = s[255];
}

__global__ __launch_bounds__(256) void scan2_kernel(int* __restrict__ part, int nb) {
  __shared__ int s[256];
  int t = threadIdx.x;
  int v = (t < nb) ? part[t] : 0;
  s[t] = v;
  __syncthreads();
  for (int off = 1; off < 256; off <<= 1) {
    int x = (t >= off) ? s[t - off] : 0;
    __syncthreads();
    s[t] += x;
    __syncthreads();
  }
  if (t < nb) part[t] = s[t] - v;
}

__global__ __launch_bounds__(256) void scan3_kernel(int* __restrict__ excl,
                                                    const int* __restrict__ part,
                                                    int* __restrict__ cursor) {
  int i = blockIdx.x * 256 + threadIdx.x;
  if (i < NN) {
    int e = excl[i] + part[i >> 8];
    excl[i] = e;
    cursor[i] = e;
  }
}

__global__ __launch_bounds__(256) void scatter_kernel(
    const int* __restrict__ senders, const int* __restrict__ recv,
    int* __restrict__ cursor, int* __restrict__ sendp,
    int* __restrict__ eperm) {
  int i = blockIdx.x * 256 + threadIdx.x;
  if (i < NE) {
    int r = recv[i];
    int pos = atomicAdd(&cursor[r], 1);
    sendp[pos] = senders[i];
    eperm[pos] = i;
  }
}

// ---------------- permute edge rows into receiver-sorted order ----------------
// One float4 per thread (4 threads/edge): fully independent random reads,
// perfectly coalesced streaming writes. High MLP replaces the serial chain
// that made hs_fused latency-bound on random reads.
__global__ __launch_bounds__(256) void epermute_kernel(
    const float* __restrict__ edges, const int* __restrict__ eperm,
    float* __restrict__ edgesP) {
  const int t = threadIdx.x;
  const int e = blockIdx.x * 64 + (t >> 2);
  if (e >= NE) return;
  const int ep = eperm[e];
  const int c = (t & 3) * 4;
  *(float4*)&edgesP[(size_t)e * 16 + c] = *(const float4*)&edges[(size_t)ep * 16 + c];
}

// ---------------- Hs[v] = sum_{e->v} relu(edgesP_e @ W0 + b0), atomic-free ----------
// Edge rows are now CONTIGUOUS per node (receiver-sorted edgesP): wave streams
// its chunk sequentially, 4-edge unroll = 256 B contiguous per iteration.
// Lean register shape: w[16][2] (32 VGPR) -> high occupancy, no spill.
DEVFN void hs_accum2(const float* __restrict__ x, const float (&w)[16][2],
                     const float2 bb, float2& a) {
  float4 x0 = *(const float4*)(x + 0);
  float4 x1 = *(const float4*)(x + 4);
  float4 x2 = *(const float4*)(x + 8);
  float4 x3 = *(const float4*)(x + 12);
  float h0 = bb.x, h1 = bb.y;
  h0 += x0.x * w[0][0];  h1 += x0.x * w[0][1];
  h0 += x0.y * w[1][0];  h1 += x0.y * w[1][1];
  h0 += x0.z * w[2][0];  h1 += x0.z * w[2][1];
  h0 += x0.w * w[3][0];  h1 += x0.w * w[3][1];
  h0 += x1.x * w[4][0];  h1 += x1.x * w[4][1];
  h0 += x1.y * w[5][0];  h1 += x1.y * w[5][1];
  h0 += x1.z * w[6][0];  h1 += x1.z * w[6][1];
  h0 += x1.w * w[7][0];  h1 += x1.w * w[7][1];
  h0 += x2.x * w[8][0];  h1 += x2.x * w[8][1];
  h0 += x2.y * w[9][0];  h1 += x2.y * w[9][1];
  h0 += x2.z * w[10][0]; h1 += x2.z * w[10][1];
  h0 += x2.w * w[11][0]; h1 += x2.w * w[11][1];
  h0 += x3.x * w[12][0]; h1 += x3.x * w[12][1];
  h0 += x3.y * w[13][0]; h1 += x3.y * w[13][1];
  h0 += x3.z * w[14][0]; h1 += x3.z * w[14][1];
  h0 += x3.w * w[15][0]; h1 += x3.w * w[15][1];
  a.x += fmaxf(h0, 0.f);
  a.y += fmaxf(h1, 0.f);
}

__global__ __launch_bounds__(256) void hs_fused_kernel(
    const float* __restrict__ edgesP, const int* __restrict__ start,
    const int* __restrict__ endc, const float* __restrict__ W0,
    const float* __restrict__ b0, float* __restrict__ Hs) {
  const int t = threadIdx.x;
  const int v = blockIdx.x * 4 + (t >> 6);  // NN % 4 == 0
  const int lane = t & 63;
  const int c = lane * 2;
  float w[16][2];
#pragma unroll
  for (int k = 0; k < 16; ++k) {
    float2 ww = *(const float2*)&W0[(size_t)k * H + c];
    w[k][0] = ww.x; w[k][1] = ww.y;
  }
  const float2 bb = *(const float2*)&b0[c];
  float2 a = make_float2(0.f, 0.f);
  int j = start[v];
  const int e = endc[v];
  for (; j + 3 < e; j += 4) {
    const float* x = &edgesP[(size_t)j * 16];
    hs_accum2(x + 0,  w, bb, a);
    hs_accum2(x + 16, w, bb, a);
    hs_accum2(x + 32, w, bb, a);
    hs_accum2(x + 48, w, bb, a);
  }
  for (; j < e; ++j)
    hs_accum2(&edgesP[(size_t)j * 16], w, bb, a);
  *(float2*)&Hs[(size_t)v * H + c] = a;
}

// ---------------- B2f[v] = Hs[v] @ Wc2 + deg[v] * bc2 ----------------
__global__ __launch_bounds__(128) void blin_kernel(
    const float* __restrict__ Hs, const float* __restrict__ Wc2,
    const float* __restrict__ bc2, const int* __restrict__ start,
    const int* __restrict__ endc, float* __restrict__ B2f) {
  __shared__ float xs[32 * 132];
  const int t = threadIdx.x;
  const int r0 = blockIdx.x * 32;
  {
    const int r = t & 31, q = t >> 5;
    int row = r0 + r;
    if (row >= NN) row = NN - 1;
    const float* src = &Hs[(size_t)row * H + q * 32];
#pragma unroll
    for (int j = 0; j < 8; ++j)
      *(float4*)&xs[r * 132 + q * 32 + j * 4] = *(const float4*)&src[j * 4];
  }
  __syncthreads();
  const int c0 = (t & 31) * 4;
  const int rbase = (t >> 5) * 8;
  const float4 bc4 = *(const float4*)&bc2[c0];
  float acc[8][4];
#pragma unroll
  for (int r = 0; r < 8; ++r) {
    int row = r0 + rbase + r;
    if (row >= NN) row = NN - 1;
    float deg = (float)(endc[row] - start[row]);
    acc[r][0] = deg * bc4.x; acc[r][1] = deg * bc4.y;
    acc[r][2] = deg * bc4.z; acc[r][3] = deg * bc4.w;
  }
  mm_block(&xs[rbase * 132], 132, H, Wc2, c0, acc);
#pragma unroll
  for (int r = 0; r < 8; ++r) {
    int row = r0 + rbase + r;
    if (row < NN)
      *(float4*)&B2f[(size_t)row * H + c0] =
          make_float4(acc[r][0], acc[r][1], acc[r][2], acc[r][3]);
  }
}

// ---------------- per-pass: S[v] = sum_{s in N(v)} n16[s]  (fp16 gather) ----------
// One WAVE per node. Lanes split 4 ways across edges (grp = lane>>4); each
// 16-lane group loads a full 256 B row (f16x8/lane). 2-deep unroll -> 8
// independent row loads in flight; dependent chain length ~deg/8.
__global__ __launch_bounds__(256) void gather_kernel(
    const _Float16* __restrict__ n16, const int* __restrict__ start,
    const int* __restrict__ endc, const int* __restrict__ sendp,
    _Float16* __restrict__ S) {
  const int t = threadIdx.x;
  const int v = blockIdx.x * 4 + (t >> 6);  // NN % 4 == 0
  const int lane = t & 63;
  const int grp = lane >> 4;
  const int c = (lane & 15) * 8;
  float a[8] = {0.f, 0.f, 0.f, 0.f, 0.f, 0.f, 0.f, 0.f};
  const int e = endc[v];
  int j = start[v];
  for (; j + 7 < e; j += 8) {
    int s0 = sendp[j + grp];
    int s1 = sendp[j + 4 + grp];
    f16x8 p0 = *(const f16x8*)&n16[(size_t)s0 * H + c];
    f16x8 p1 = *(const f16x8*)&n16[(size_t)s1 * H + c];
#pragma unroll
    for (int i = 0; i < 8; ++i) a[i] += (float)p0[i] + (float)p1[i];
  }
  for (; j < e; j += 4) {
    int jj = j + grp;
    if (jj < e) {
      int s0 = sendp[jj];
      f16x8 p0 = *(const f16x8*)&n16[(size_t)s0 * H + c];
#pragma unroll
      for (int i = 0; i < 8; ++i) a[i] += (float)p0[i];
    }
  }
#pragma unroll
  for (int i = 0; i < 8; ++i) {
    a[i] += __shfl_xor(a[i], 16);
    a[i] += __shfl_xor(a[i], 32);
  }
  if (lane < 16) {
    f16x8 o;
#pragma unroll
    for (int i = 0; i < 8; ++i) o[i] = (_Float16)a[i];
    *(f16x8*)&S[(size_t)v * H + c] = o;
  }
}

// ---------------- MFMA node update ----------------
// pre-act = n@W0t + S@Wf + B2 + b0 ; h = relu(pre-act)
// out = LN(h@W1 + n@Wn + b1)
__global__ __launch_bounds__(256) void node_mfma_kernel(
    const _Float16* __restrict__ n16, const _Float16* __restrict__ S16,
    const _Float16* __restrict__ B2pk,
    const _Float16* __restrict__ pkW0t, const _Float16* __restrict__ pkWf,
    const float* __restrict__ b0,
    const _Float16* __restrict__ pkW1, const _Float16* __restrict__ pkWn,
    const float* __restrict__ b1,
    const float* __restrict__ ln_g, const float* __restrict__ ln_b,
    _Float16* __restrict__ nout) {
  __shared__ _Float16 lds[4][16 * 136];
  const int t = threadIdx.x;
  const int wave = t >> 6, lane = t & 63;
  const int row0 = blockIdx.x * 64 + wave * 16;
  const int quad = lane >> 4, m16 = lane & 15;
  _Float16* hlds = &lds[wave][0];

  int arow = row0 + m16;
  if (arow >= NN) arow = NN - 1;
  const _Float16* nrow = &n16[(size_t)arow * H + quad * 8];
  const _Float16* srow = &S16[(size_t)arow * H + quad * 8];

  const int tile = blockIdx.x * 4 + wave;
  const _Float16* b2l = &B2pk[((size_t)tile * 64 + lane) * 32];
  f32x4 acc[8];
#pragma unroll
  for (int ct = 0; ct < 8; ++ct) {
    float bb = b0[ct * 16 + m16];
    f16x4 bv = *(const f16x4*)(b2l + ct * 4);
    acc[ct] = (f32x4){bb + (float)bv[0], bb + (float)bv[1],
                      bb + (float)bv[2], bb + (float)bv[3]};
  }
#pragma unroll
  for (int ks = 0; ks < 4; ++ks) {
    f16x8 an = *(const f16x8*)(nrow + ks * 32);
    f16x8 as = *(const f16x8*)(srow + ks * 32);
    const _Float16* bp0 = pkW0t + ((size_t)ks * 8 * 64 + lane) * 8;
    const _Float16* bpf = pkWf + ((size_t)ks * 8 * 64 + lane) * 8;
#pragma unroll
    for (int ct = 0; ct < 8; ++ct) {
      f16x8 bw0 = *(const f16x8*)(bp0 + ct * 512);
      acc[ct] = __builtin_amdgcn_mfma_f32_16x16x32_f16(an, bw0, acc[ct], 0, 0, 0);
      f16x8 bwf = *(const f16x8*)(bpf + ct * 512);
      acc[ct] = __builtin_amdgcn_mfma_f32_16x16x32_f16(as, bwf, acc[ct], 0, 0, 0);
    }
  }
#pragma unroll
  for (int ct = 0; ct < 8; ++ct) {
#pragma unroll
    for (int q = 0; q < 4; ++q)
      hlds[(quad * 4 + q) * 136 + ct * 16 + m16] =
          (_Float16)fmaxf(acc[ct][q], 0.f);
  }
  __syncthreads();

  const _Float16* hrow = &hlds[m16 * 136 + quad * 8];
  f32x4 acc2[8];
#pragma unroll
  for (int ct = 0; ct < 8; ++ct) {
    float bb = b1[ct * 16 + m16];
    acc2[ct] = (f32x4){bb, bb, bb, bb};
  }
#pragma unroll
  for (int ks = 0; ks < 4; ++ks) {
    f16x8 ah = *(const f16x8*)(hrow + ks * 32);
    f16x8 an = *(const f16x8*)(nrow + ks * 32);
    const _Float16* bp1 = pkW1 + ((size_t)ks * 8 * 64 + lane) * 8;
    const _Float16* bpn = pkWn + ((size_t)ks * 8 * 64 + lane) * 8;
#pragma unroll
    for (int ct = 0; ct < 8; ++ct) {
      f16x8 b1f = *(const f16x8*)(bp1 + ct * 512);
      acc2[ct] = __builtin_amdgcn_mfma_f32_16x16x32_f16(ah, b1f, acc2[ct], 0, 0, 0);
      f16x8 bnf = *(const f16x8*)(bpn + ct * 512);
      acc2[ct] = __builtin_amdgcn_mfma_f32_16x16x32_f16(an, bnf, acc2[ct], 0, 0, 0);
    }
  }

  float gv[8], bv[8];
#pragma unroll
  for (int ct = 0; ct < 8; ++ct) {
    gv[ct] = ln_g[ct * 16 + m16];
    bv[ct] = ln_b[ct * 16 + m16];
  }
  __syncthreads();
#pragma unroll
  for (int q = 0; q < 4; ++q) {
    float s1 = 0.f, s2 = 0.f;
#pragma unroll
    for (int ct = 0; ct < 8; ++ct) {
      float v = acc2[ct][q];
      s1 += v; s2 += v * v;
    }
#pragma unroll
    for (int m = 1; m <= 8; m <<= 1) {
      s1 += __shfl_xor(s1, m);
      s2 += __shfl_xor(s2, m);
    }
    float mu = s1 * (1.f / 128.f);
    float var = s2 * (1.f / 128.f) - mu * mu;
    float rs = rsqrtf(var + LN_EPS);
#pragma unroll
    for (int ct = 0; ct < 8; ++ct) {
      float o = (acc2[ct][q] - mu) * rs * gv[ct] + bv[ct];
      hlds[(quad * 4 + q) * 136 + ct * 16 + m16] = (_Float16)o;
    }
  }
  __syncthreads();

  {
    int lr = lane >> 2;
    int cc = (lane & 3) * 32;
    const _Float16* src = &hlds[lr * 136 + cc];
    int orow = row0 + lr;
    if (orow < NN) {
      _Float16* dst = &nout[(size_t)orow * H + cc];
      *(f16x8*)(dst + 0)  = *(const f16x8*)(src + 0);
      *(f16x8*)(dst + 8)  = *(const f16x8*)(src + 8);
      *(f16x8*)(dst + 16) = *(const f16x8*)(src + 16);
      *(f16x8*)(dst + 24) = *(const f16x8*)(src + 24);
    }
  }
}

// ---------------- decoder (fp16 node input) ----------------
__global__ __launch_bounds__(128) void decode_kernel(
    const _Float16* __restrict__ n, const float* __restrict__ W0,
    const float* __restrict__ b0, const float* __restrict__ W1,
    const float* __restrict__ b1, float* __restrict__ out) {
  __shared__ float xs[32 * 132];
  __shared__ float hs[32 * 132];
  const int t = threadIdx.x;
  const int r0 = blockIdx.x * 32;
  {
    const int r = t & 31, q = t >> 5;
    int row = r0 + r;
    if (row >= NN) row = NN - 1;
    const _Float16* src = &n[(size_t)row * H + q * 32];
#pragma unroll
    for (int j = 0; j < 4; ++j) {
      f16x8 v8 = *(const f16x8*)&src[j * 8];
#pragma unroll
      for (int i = 0; i < 8; ++i)
        xs[r * 132 + q * 32 + j * 8 + i] = (float)v8[i];
    }
  }
  __syncthreads();
  const int c0 = (t & 31) * 4;
  const int rbase = (t >> 5) * 8;
  float acc[8][4];
  {
    float4 bb = *(const float4*)&b0[c0];
#pragma unroll
    for (int r = 0; r < 8; ++r) { acc[r][0] = bb.x; acc[r][1] = bb.y; acc[r][2] = bb.z; acc[r][3] = bb.w; }
  }
  mm_block(&xs[rbase * 132], 132, H, W0, c0, acc);
#pragma unroll
  for (int r = 0; r < 8; ++r) {
    float4 h;
    h.x = fmaxf(acc[r][0], 0.f); h.y = fmaxf(acc[r][1], 0.f);
    h.z = fmaxf(acc[r][2], 0.f); h.w = fmaxf(acc[r][3], 0.f);
    *(float4*)&hs[(rbase + r) * 132 + c0] = h;
  }
  __syncthreads();
  if (t < 64) {
    int r = t >> 1, c = t & 1;
    float s = b1[c];
    for (int k = 0; k < H; ++k) s += hs[r * 132 + k] * W1[k * 2 + c];
    int row = r0 + r;
    if (row < NN) out[(size_t)row * 2 + c] = s;
  }
}

__global__ __launch_bounds__(256) void zero_kernel(float4* __restrict__ p, int n4) {
  int i = blockIdx.x * 256 + threadIdx.x;
  if (i < n4) p[i] = make_float4(0.f, 0.f, 0.f, 0.f);
}

}  // namespace

extern "C" void kernel_launch(void* const* d_in, const int* in_sizes, int n_in,
                              void* d_out, int out_size, void* d_ws, size_t ws_size,
                              hipStream_t stream) {
  const float* nodes     = (const float*)d_in[0];
  const float* edges     = (const float*)d_in[1];
  const int*   senders   = (const int*)d_in[2];
  const int*   receivers = (const int*)d_in[3];
  const float* enc_n_W0 = (const float*)d_in[4];
  const float* enc_n_b0 = (const float*)d_in[5];
  const float* enc_n_W1 = (const float*)d_in[6];
  const float* enc_n_b1 = (const float*)d_in[7];
  const float* enc_e_W0 = (const float*)d_in[8];
  const float* enc_e_b0 = (const float*)d_in[9];
  const float* enc_e_W1 = (const float*)d_in[10];
  const float* enc_e_b1 = (const float*)d_in[11];
  const float* W_msg    = (const float*)d_in[12];
  const float* node_W0  = (const float*)d_in[13];
  const float* node_b0  = (const float*)d_in[14];
  const float* node_W1  = (const float*)d_in[15];
  const float* node_b1  = (const float*)d_in[16];
  const float* W_node   = (const float*)d_in[17];
  const float* ln_g     = (const float*)d_in[18];
  const float* ln_b     = (const float*)d_in[19];
  const float* dec_W0   = (const float*)d_in[20];
  const float* dec_b0   = (const float*)d_in[21];
  const float* dec_W1   = (const float*)d_in[22];
  const float* dec_b1   = (const float*)d_in[23];
  float* out = (float*)d_out;

  const float* Wt  = W_msg;                // rows 0..127 of W_msg
  const float* Wb  = W_msg + 128 * H;      // rows 128..255
  const float* W0t = node_W0;              // rows 0..127 of node_W0
  const float* W0b = node_W0 + 128 * H;    // rows 128..255

  const int mfmaBlocks = (NN + 63) / 64;   // 782
  const int nTiles     = mfmaBlocks * 4;

  // workspace layout (~175 MB)
  float* Hs     = (float*)d_ws;                        // NN*H f32
  float* B2f    = Hs + (size_t)NN * H;                 // NN*H f32
  float* edgesP = B2f + (size_t)NN * H;                // NE*16 f32 (38.4 MB)
  float* Wc     = edgesP + (size_t)NE * 16;            // 128*128 f32
  float* Wc2    = Wc + 128 * H;
  float* Wf32   = Wc2 + 128 * H;
  float* bc     = Wf32 + 128 * H;                      // 128
  float* bc2    = bc + 128;                            // 128
  _Float16* n16a  = (_Float16*)(bc2 + 128);            // NN*H f16
  _Float16* n16b  = n16a + (size_t)NN * H;
  _Float16* S16   = n16b + (size_t)NN * H;
  _Float16* B2pk  = S16 + (size_t)NN * H;              // nTiles*64*32 f16
  _Float16* pkW0t = B2pk + (size_t)nTiles * 64 * 32;
  _Float16* pkWf  = pkW0t + 128 * H;
  _Float16* pkW1  = pkWf + 128 * H;
  _Float16* pkWn  = pkW1 + 128 * H;
  int* cnt    = (int*)(pkWn + 128 * H);
  int* excl   = cnt + NN;
  int* cursor = excl + NN;
  int* part   = cursor + NN;               // 256
  int* sendp  = part + 256;                // NE
  int* eperm  = sendp + NE;                // NE

  const int nodeBlocks = (NN + 31) / 32;     // 1563
  const int scanBlocks = (NN + 255) / 256;   // 196
  const int neBlocks   = (NE + 255) / 256;   // 2344

  // --- one-time: sort edges by receiver; permute edge rows ---
  zero_kernel<<<(NN / 4 + 255) / 256, 256, 0, stream>>>((float4*)cnt, NN / 4);
  hist_kernel<<<neBlocks, 256, 0, stream>>>(receivers, cnt);
  scan1_kernel<<<scanBlocks, 256, 0, stream>>>(cnt, excl, part);
  scan2_kernel<<<1, 256, 0, stream>>>(part, scanBlocks);
  scan3_kernel<<<scanBlocks, 256, 0, stream>>>(excl, part, cursor);
  scatter_kernel<<<neBlocks, 256, 0, stream>>>(senders, receivers, cursor, sendp, eperm);
  epermute_kernel<<<(NE + 63) / 64, 256, 0, stream>>>(edges, eperm, edgesP);

  // --- fold chains:  Wc = W1e@Wb;  Wc2 = Wc@W0b;  Wf = Wt@W0b;  bc2 = (b1e@Wb)@W0b ---
  linear_kernel<<<4, 128, 0, stream>>>(enc_e_W1, Wb, Wc, 128);
  vecmat_kernel<<<1, 128, 0, stream>>>(enc_e_b1, Wb, bc);
  linear_kernel<<<4, 128, 0, stream>>>(Wc, W0b, Wc2, 128);
  vecmat_kernel<<<1, 128, 0, stream>>>(bc, W0b, bc2);
  linear_kernel<<<4, 128, 0, stream>>>(Wt, W0b, Wf32, 128);
  prepack_kernel<<<dim3(4, 8), 64, 0, stream>>>(W0t, pkW0t);
  prepack_kernel<<<dim3(4, 8), 64, 0, stream>>>(Wf32, pkWf);
  prepack_kernel<<<dim3(4, 8), 64, 0, stream>>>(node_W1, pkW1);
  prepack_kernel<<<dim3(4, 8), 64, 0, stream>>>(W_node, pkWn);

  encoder_kernel<32><<<nodeBlocks, 128, 0, stream>>>(
      nodes, enc_n_W0, enc_n_b0, enc_n_W1, enc_n_b1, n16a, NN);
  hs_fused_kernel<<<NN / 4, 256, 0, stream>>>(
      edgesP, excl, cursor, enc_e_W0, enc_e_b0, Hs);
  blin_kernel<<<nodeBlocks, 128, 0, stream>>>(Hs, Wc2, bc2, excl, cursor, B2f);
  packc_kernel<<<NN / 16, 64, 0, stream>>>(B2f, B2pk);

  // --- 5 weight-tied passes ---
  _Float16* ncur = n16a;
  _Float16* nnxt = n16b;
  for (int p = 0; p < 5; ++p) {
    gather_kernel<<<NN / 4, 256, 0, stream>>>(ncur, excl, cursor, sendp, S16);
    node_mfma_kernel<<<mfmaBlocks, 256, 0, stream>>>(
        ncur, S16, B2pk, pkW0t, pkWf, node_b0, pkW1, pkWn, node_b1,
        ln_g, ln_b, nnxt);
    _Float16* tmp = ncur; ncur = nnxt; nnxt = tmp;
  }

  decode_kernel<<<nodeBlocks, 128, 0, stream>>>(ncur, dec_W0, dec_b0, dec_W1, dec_b1, out);
}